// Round 2
// baseline (267.494 us; speedup 1.0000x reference)
//
#include <hip/hip_runtime.h>

// Problem: z [32,256,32,32] fp32, codebook [1024,256] fp32
constexpr int D_ = 256;
constexpr int K_ = 1024;
constexpr int P_ = 1024;
constexpr int N_ = 32768;

// d_out layout (float32): z_q [8388608] ++ idx-as-float [32768] ++ loss [1]
constexpr int IDX_OFF  = 8388608;
constexpr int LOSS_OFF = 8421376;

// scratch parked in d_out's z_q region (gather overwrites it LAST):
constexpr int CB16_OFF = 0;        // fp16-split swizzled cb: 262144 floats
constexpr int CN_OFF   = 262400;   // cnorm [1024]
constexpr int ZN_OFF   = 263424;   // zn [32768]
constexpr int CNT_OFF  = 296448;   // worklist counter (int)
constexpr int WL_OFF   = 296449;   // worklist [<=32768] (int row ids)

constexpr float RESCUE_MARGIN = 1e-4f;  // ~3.3 ulp(256)

typedef _Float16 half8 __attribute__((ext_vector_type(8)));
typedef float f32x4 __attribute__((ext_vector_type(4)));

__device__ __forceinline__ void stage16(const float* g, float* l) {
  // async global->LDS, 16B per lane. LDS dest must be wave-uniform base;
  // HW adds lane*16. Global src is per-lane.
  __builtin_amdgcn_global_load_lds(
      (const __attribute__((address_space(1))) unsigned int*)g,
      (__attribute__((address_space(3))) unsigned int*)l, 16, 0, 0);
}

// ---------------------------------------------------------------------------
// prep: blk<512: zn[row]=||z||^2 (PROVEN bit order); 512..1535: cnorm fp64
// (proven); 1536..1599: cb fp16-split swizzle. blk0 zeroes loss + counter.
__global__ __launch_bounds__(64) void vq_prep(const float* __restrict__ z,
                                              const float* __restrict__ cb,
                                              float* __restrict__ scratch,
                                              float* __restrict__ loss) {
  const int blk = blockIdx.x;
  const int lane = threadIdx.x;
  if (blk < 512) {
    const int n0 = blk * 64;
    const int b = n0 >> 10, p0 = n0 & (P_ - 1);
    const float* zp = z + (size_t)b * (D_ * P_) + p0 + lane;
    float a8[8];
    #pragma unroll
    for (int i = 0; i < 8; ++i) a8[i] = 0.0f;
    for (int oct = 0; oct < 32; ++oct) {
      #pragma unroll
      for (int i = 0; i < 8; ++i) {
        float v = zp[(size_t)(oct * 8 + i) * P_];
        a8[i] = fmaf(v, v, a8[i]);
      }
    }
    scratch[ZN_OFF + n0 + lane] = ((a8[0] + a8[1]) + (a8[2] + a8[3])) +
                                  ((a8[4] + a8[5]) + (a8[6] + a8[7]));
    if (blk == 0 && lane == 0) {
      *loss = 0.0f;
      ((int*)(scratch + CNT_OFF))[0] = 0;
    }
  } else if (blk < 1536) {
    const int k = blk - 512;
    const float* row = cb + (size_t)k * D_;
    double s = 0.0;
    #pragma unroll
    for (int i = 0; i < 4; ++i) {
      double v = (double)row[lane + i * 64];
      s = fma(v, v, s);
    }
    #pragma unroll
    for (int off = 32; off; off >>= 1) s += __shfl_down(s, off, 64);
    if (lane == 0) scratch[CN_OFF + k] = (float)s;
  } else {
    const int kt = blk - 1536;
    const int k = kt * 16 + (lane & 15);
    const int quad = lane >> 4;
    _Float16* cw = (_Float16*)(scratch + CB16_OFF);
    for (int ds = 0; ds < 8; ++ds) {
      const float* src = cb + (size_t)k * D_ + ds * 32 + quad * 8;
      half8 h, lo;
      #pragma unroll
      for (int j = 0; j < 8; ++j) {
        const float v = src[j] * 1024.0f;   // scale keeps lo out of subnormals
        const _Float16 hh = (_Float16)v;
        h[j] = hh;
        lo[j] = (_Float16)(v - (float)hh);
      }
      const int s = kt * 8 + ds;
      *(half8*)(cw + ((size_t)(s * 2 + 0) * 64 + lane) * 8) = h;
      *(half8*)(cw + ((size_t)(s * 2 + 1) * 64 + lane) * 8) = lo;
    }
  }
}

// ---------------------------------------------------------------------------
// main: fp16-split MFMA distance + argmin + worklist flagging.
// R10: 2-wave (128-thread) blocks, each wave owns TWO 16-row tiles (block
// still = 64 rows, grid 512 => 2 independent blocks/CU whose barrier/stage
// bubbles cover each other). Per wave per kt: 16 ds_read_b128 now feed 48
// MFMA (was 16:24 -> LDS-read-bound); and the fp16-split products go to 3
// SEPARATE accumulators per tile (aH=Ah*Bh, aM=Ah*Bl, aL=Al*Bh, summed in
// epilogue) => 6 independent MFMA chains/wave, reuse distance 6 issues --
// kills the 12-deep dependent-MFMA chain that exposed MFMA latency in R9.
// Ring-3 LDS staging + counted vmcnt (never 0 mid-loop) + raw s_barrier
// preserved from R9 (proven correct, absmax 0).
__global__ __launch_bounds__(128, 2) void vq_mfma(const float* __restrict__ z,
                                                  float* __restrict__ scratch,
                                                  float* __restrict__ idxf) {
  const int t = threadIdx.x;
  const int w = t >> 6;        // wave id: owns rows [w*32, w*32+32)
  const int l = t & 63;
  const int quad = l >> 4;
  const int col = l & 15;
  const int n0 = blockIdx.x * 64;
  const int b = n0 >> 10;
  const int p0 = n0 & (P_ - 1);

  const float* __restrict__ cbsw_f = scratch + CB16_OFF;
  const float* __restrict__ cnorm = scratch + CN_OFF;
  const float* __restrict__ zn = scratch + ZN_OFF;

  __shared__ alignas(16) float Bbuf[3][4096];   // 3 x 16KB B ring
  __shared__ alignas(16) float cnLds[1024];     // cnorm copy
  float* Azs = &Bbuf[2][0];   // prologue alias [64][33] = 2112 floats < 4096
                              // (Bbuf[2] first written by stage(kt=2), issued
                              //  after the iter-0 barrier => no overlap)

  // cnorm -> LDS (visibility sealed by the prologue __syncthreads below)
  *(float4*)(cnLds + t * 8)     = *(const float4*)(cnorm + t * 8);
  *(float4*)(cnLds + t * 8 + 4) = *(const float4*)(cnorm + t * 8 + 4);

  // zn for this wave's tile rows (additive per-row constant)
  float znr[2][4];
  #pragma unroll
  for (int rt = 0; rt < 2; ++rt) {
    const float4 znv = *(const float4*)(zn + n0 + w * 32 + rt * 16 + quad * 4);
    znr[rt][0] = znv.x; znr[rt][1] = znv.y;
    znr[rt][2] = znv.z; znr[rt][3] = znv.w;
  }

  // ---- A prologue: stage z 32-d chunks through Azs, fp16-split to regs ----
  half8 Ah[2][8], Al[2][8];
  for (int ds = 0; ds < 8; ++ds) {
    __syncthreads();
    #pragma unroll
    for (int i = 0; i < 16; ++i) {
      const int dloc = w * 16 + i;   // 2 waves x 16 d cover the 32-d chunk
      Azs[l * 33 + dloc] =
          z[(size_t)b * (D_ * P_) + (size_t)(ds * 32 + dloc) * P_ + p0 + l];
    }
    __syncthreads();
    #pragma unroll
    for (int rt = 0; rt < 2; ++rt) {
      const float* src = &Azs[(w * 32 + rt * 16 + col) * 33 + quad * 8];
      half8 h, lo;
      #pragma unroll
      for (int j = 0; j < 8; ++j) {
        const float v = src[j];
        const _Float16 hh = (_Float16)v;
        h[j] = hh;
        lo[j] = (_Float16)(v - (float)hh);
      }
      Ah[rt][ds] = h;
      Al[rt][ds] = lo;
    }
  }

  // drain the prologue's register-bound VMEM (cnorm/zn/z loads) so the
  // in-loop vmcnt counting tracks ONLY stage16 ops.
  asm volatile("s_waitcnt vmcnt(0)" ::: "memory");

  // ---- prologue B stages: kt=0 -> buf0 (all 8 loads first!), kt=1 -> buf1 --
  {
    const float* g0 = cbsw_f + l * 4;
    #pragma unroll
    for (int j = 0; j < 8; ++j) {
      const int chunk = w * 8 + j;
      stage16(g0 + chunk * 256, &Bbuf[0][chunk * 256]);
    }
    #pragma unroll
    for (int j = 0; j < 8; ++j) {
      const int chunk = w * 8 + j;
      stage16(g0 + 4096 + chunk * 256, &Bbuf[1][chunk * 256]);
    }
  }

  float m1[2][4], m2v[2][4];
  int i1[2][4];
  #pragma unroll
  for (int rt = 0; rt < 2; ++rt)
    #pragma unroll
    for (int r = 0; r < 4; ++r) { m1[rt][r] = 1e30f; m2v[rt][r] = 1e30f; i1[rt][r] = 0; }

  // rotate 3 base pointers instead of runtime-indexing Bbuf[cur]
  float* bp0 = &Bbuf[0][0];   // consume
  float* bp1 = &Bbuf[1][0];   // landed next
  float* bp2 = &Bbuf[2][0];   // stage target
  const float* gs = cbsw_f + 2 * 4096 + l * 4;   // next tile to stage (kt=2)
  const float* cnp = cnLds;
  int kg = col;

  for (int kt = 0; kt < 64; ++kt) {
    // per-wave: 8 stage16 per tile. prologue issued 16; steady state: wait
    // vmcnt(8) retires the oldest 8 = stage(kt); barrier makes buf[kt]
    // visible to both waves and retires all readers of the stage target.
    if (kt < 63) {
      asm volatile("s_waitcnt vmcnt(8)" ::: "memory");
    } else {
      asm volatile("s_waitcnt vmcnt(0)" ::: "memory");
    }
    __builtin_amdgcn_s_barrier();
    __builtin_amdgcn_sched_barrier(0);

    if (kt < 62) {   // prefetch tile kt+2 into bp2
      #pragma unroll
      for (int j = 0; j < 8; ++j) {
        const int chunk = w * 8 + j;
        stage16(gs + chunk * 256, bp2 + chunk * 256);
      }
      gs += 4096;
    }

    const float cnf = cnp[col];

    f32x4 aH0 = {0.f,0.f,0.f,0.f}, aM0 = {0.f,0.f,0.f,0.f}, aL0 = {0.f,0.f,0.f,0.f};
    f32x4 aH1 = {0.f,0.f,0.f,0.f}, aM1 = {0.f,0.f,0.f,0.f}, aL1 = {0.f,0.f,0.f,0.f};

    __builtin_amdgcn_s_setprio(1);
    #pragma unroll
    for (int ds = 0; ds < 8; ++ds) {
      const half8 bh = *(const half8*)(bp0 + (ds * 2 + 0) * 256 + l * 4);
      const half8 bl = *(const half8*)(bp0 + (ds * 2 + 1) * 256 + l * 4);
      // 6 mutually independent MFMAs per ds (3 chains x 2 tiles)
      aH0 = __builtin_amdgcn_mfma_f32_16x16x32_f16(Ah[0][ds], bh, aH0, 0, 0, 0);
      aH1 = __builtin_amdgcn_mfma_f32_16x16x32_f16(Ah[1][ds], bh, aH1, 0, 0, 0);
      aM0 = __builtin_amdgcn_mfma_f32_16x16x32_f16(Ah[0][ds], bl, aM0, 0, 0, 0);
      aM1 = __builtin_amdgcn_mfma_f32_16x16x32_f16(Ah[1][ds], bl, aM1, 0, 0, 0);
      aL0 = __builtin_amdgcn_mfma_f32_16x16x32_f16(Al[0][ds], bh, aL0, 0, 0, 0);
      aL1 = __builtin_amdgcn_mfma_f32_16x16x32_f16(Al[1][ds], bh, aL1, 0, 0, 0);
    }
    __builtin_amdgcn_s_setprio(0);

    #pragma unroll
    for (int r = 0; r < 4; ++r) {
      const float s0 = fmaf((aH0[r] + aM0[r]) + aL0[r], -0x1p-9f, znr[0][r] + cnf);
      if (s0 < m1[0][r]) { m2v[0][r] = m1[0][r]; m1[0][r] = s0; i1[0][r] = kg; }  // k asc: strict <
      else if (s0 < m2v[0][r]) m2v[0][r] = s0;
      const float s1 = fmaf((aH1[r] + aM1[r]) + aL1[r], -0x1p-9f, znr[1][r] + cnf);
      if (s1 < m1[1][r]) { m2v[1][r] = m1[1][r]; m1[1][r] = s1; i1[1][r] = kg; }
      else if (s1 < m2v[1][r]) m2v[1][r] = s1;
    }

    cnp += 16;
    kg += 16;
    float* tmp = bp0; bp0 = bp1; bp1 = bp2; bp2 = tmp;
  }

  // ---- cross-col top-2 butterfly (exact set merge, order-independent) ----
  #pragma unroll
  for (int off = 1; off <= 8; off <<= 1) {
    #pragma unroll
    for (int rt = 0; rt < 2; ++rt)
      #pragma unroll
      for (int r = 0; r < 4; ++r) {
        const float o1 = __shfl_xor(m1[rt][r], off, 64);
        const float o2 = __shfl_xor(m2v[rt][r], off, 64);
        const int oi = __shfl_xor(i1[rt][r], off, 64);
        if (o1 < m1[rt][r]) { m2v[rt][r] = fminf(m1[rt][r], o2); m1[rt][r] = o1; i1[rt][r] = oi; }
        else if (o1 == m1[rt][r]) { i1[rt][r] = min(i1[rt][r], oi); m2v[rt][r] = m1[rt][r]; }
        else { m2v[rt][r] = fminf(m2v[rt][r], o1); }
      }
  }

  if (col == 0) {
    int* cnt = (int*)(scratch + CNT_OFF);
    int* wl = (int*)(scratch + WL_OFF);
    #pragma unroll
    for (int rt = 0; rt < 2; ++rt)
      #pragma unroll
      for (int r = 0; r < 4; ++r) {
        const int n = n0 + w * 32 + rt * 16 + quad * 4 + r;
        idxf[n] = (float)i1[rt][r];
        if (m2v[rt][r] - m1[rt][r] < RESCUE_MARGIN) {
          const int pos = atomicAdd(cnt, 1);
          wl[pos] = n;
        }
      }
  }
}

// ---------------------------------------------------------------------------
// rescue (BATCHED): 8 rows per codebook sweep. Stage 8 z-rows in LDS; thread
// owns k = 4*tid..4*tid+3 (one pass covers K=1024) with 8x4 = 32 independent
// fma chains -> per d4-step: 4 global float4 + 8 LDS broadcasts feed 128
// fmas (latency hidden by arithmetic, nothing for the compiler to fight).
// Bit-exactness: per (row,k) chain is ascending-d sequential; k ascending
// per thread (strict <); (value,index)-lexicographic block reduction.
__global__ __launch_bounds__(256, 4) void vq_rescue(const float* __restrict__ z,
                                                    const float* __restrict__ cb,
                                                    const float* __restrict__ scratch,
                                                    float* __restrict__ idxf) {
  const int tid = threadIdx.x;
  const float* cnorm = scratch + CN_OFF;
  const float* zn = scratch + ZN_OFF;
  const int count = ((const int*)(scratch + CNT_OFF))[0];
  const int* wl = (const int*)(scratch + WL_OFF);

  __shared__ alignas(16) float zb[8][D_];
  __shared__ int nrow[8];
  __shared__ float rv[256];
  __shared__ int ri[256];

  for (int base = blockIdx.x * 8; base < count; base += gridDim.x * 8) {
    const int take = min(8, count - base);
    if (tid < 8) nrow[tid] = wl[base + (tid < take ? tid : 0)];
    __syncthreads();
    #pragma unroll
    for (int r = 0; r < 8; ++r) {
      const int n = nrow[r];
      const int b = n >> 10, p = n & (P_ - 1);
      zb[r][tid] = z[(size_t)b * (D_ * P_) + (size_t)tid * P_ + p];
    }
    __syncthreads();

    const int k0 = tid * 4;
    const float4* __restrict__ cr0 = (const float4*)(cb + (size_t)(k0 + 0) * D_);
    const float4* __restrict__ cr1 = (const float4*)(cb + (size_t)(k0 + 1) * D_);
    const float4* __restrict__ cr2 = (const float4*)(cb + (size_t)(k0 + 2) * D_);
    const float4* __restrict__ cr3 = (const float4*)(cb + (size_t)(k0 + 3) * D_);

    float acc[8][4];
    #pragma unroll
    for (int r = 0; r < 8; ++r)
      #pragma unroll
      for (int j = 0; j < 4; ++j) acc[r][j] = 0.0f;

    for (int d4 = 0; d4 < 64; ++d4) {
      const float4 v0 = cr0[d4], v1 = cr1[d4], v2 = cr2[d4], v3 = cr3[d4];
      #pragma unroll
      for (int r = 0; r < 8; ++r) {
        const float4 zv = ((const float4*)zb[r])[d4];   // LDS broadcast
        acc[r][0] = fmaf(zv.x, v0.x, acc[r][0]);
        acc[r][0] = fmaf(zv.y, v0.y, acc[r][0]);
        acc[r][0] = fmaf(zv.z, v0.z, acc[r][0]);
        acc[r][0] = fmaf(zv.w, v0.w, acc[r][0]);
        acc[r][1] = fmaf(zv.x, v1.x, acc[r][1]);
        acc[r][1] = fmaf(zv.y, v1.y, acc[r][1]);
        acc[r][1] = fmaf(zv.z, v1.z, acc[r][1]);
        acc[r][1] = fmaf(zv.w, v1.w, acc[r][1]);
        acc[r][2] = fmaf(zv.x, v2.x, acc[r][2]);
        acc[r][2] = fmaf(zv.y, v2.y, acc[r][2]);
        acc[r][2] = fmaf(zv.z, v2.z, acc[r][2]);
        acc[r][2] = fmaf(zv.w, v2.w, acc[r][2]);
        acc[r][3] = fmaf(zv.x, v3.x, acc[r][3]);
        acc[r][3] = fmaf(zv.y, v3.y, acc[r][3]);
        acc[r][3] = fmaf(zv.z, v3.z, acc[r][3]);
        acc[r][3] = fmaf(zv.w, v3.w, acc[r][3]);
      }
    }

    for (int r = 0; r < 8; ++r) {
      const int n = nrow[r];
      const float zA = zn[n];
      float bv = 1e30f;
      int bi = 0x7fffffff;
      #pragma unroll
      for (int j = 0; j < 4; ++j) {               // k ascending -> strict <
        const float A = zA + cnorm[k0 + j];
        const float s = A - 2.0f * acc[r][j];
        if (s < bv) { bv = s; bi = k0 + j; }
      }
      rv[tid] = bv; ri[tid] = bi;
      __syncthreads();
      for (int off = 128; off >= 1; off >>= 1) {
        if (tid < off) {
          const float ov = rv[tid + off];
          const int oi = ri[tid + off];
          if (ov < rv[tid] || (ov == rv[tid] && oi < ri[tid])) { rv[tid] = ov; ri[tid] = oi; }
        }
        __syncthreads();
      }
      if (tid == 0 && r < take) idxf[n] = (float)ri[0];
      __syncthreads();
    }
  }
}

// ---------------------------------------------------------------------------
// gather: z_q = codebook[idx] into NCHW + loss; STE write out = z + (v - z).
__global__ __launch_bounds__(256) void vq_gather(const float* __restrict__ z,
                                                 const float* __restrict__ cb,
                                                 const float* __restrict__ idxf,
                                                 float* __restrict__ out,
                                                 float* __restrict__ loss) {
  const int tid = threadIdx.x;
  const int lane = tid & 63;
  const int w = tid >> 6;
  const int n0 = blockIdx.x * 64;
  const int b = n0 >> 10;
  const int p0 = n0 & (P_ - 1);
  const int p = p0 + lane;

  const int idx = (int)(idxf[n0 + lane] + 0.5f);
  const float4* crow4 = (const float4*)(cb + (size_t)idx * D_);
  const size_t base = (size_t)b * (D_ * P_) + p;

  float acc = 0.0f;
  #pragma unroll 4
  for (int ci = 0; ci < 16; ++ci) {
    const float4 v = crow4[w * 16 + ci];
    const int c = w * 64 + ci * 4;
    const float vv[4] = {v.x, v.y, v.z, v.w};
    #pragma unroll
    for (int u = 0; u < 4; ++u) {
      const size_t a = base + (size_t)(c + u) * P_;
      const float zv = z[a];
      const float d = vv[u] - zv;
      out[a] = zv + d;                  // fl32 STE, bit-exact
      acc = fmaf(d, d, acc);
    }
  }
  #pragma unroll
  for (int off = 32; off; off >>= 1) acc += __shfl_down(acc, off, 64);
  __shared__ float wsum[4];
  if (lane == 0) wsum[w] = acc;
  __syncthreads();
  if (tid == 0) {
    float s = wsum[0] + wsum[1] + wsum[2] + wsum[3];
    atomicAdd(loss, s * (1.25f / 8388608.0f));
  }
}

// ---------------------------------------------------------------------------
extern "C" void kernel_launch(void* const* d_in, const int* in_sizes, int n_in,
                              void* d_out, int out_size, void* d_ws, size_t ws_size,
                              hipStream_t stream) {
  const float* z = (const float*)d_in[0];
  const float* cb = (const float*)d_in[1];
  float* out = (float*)d_out;

  vq_prep<<<1600, 64, 0, stream>>>(z, cb, out, out + LOSS_OFF);
  vq_mfma<<<N_ / 64, 128, 0, stream>>>(z, out, out + IDX_OFF);
  vq_rescue<<<128, 256, 0, stream>>>(z, cb, out, out + IDX_OFF);
  vq_gather<<<N_ / 64, 256, 0, stream>>>(z, cb, out + IDX_OFF, out, out + LOSS_OFF);
}

// Round 3
// 226.710 us; speedup vs baseline: 1.1799x; 1.1799x over previous
//
#include <hip/hip_runtime.h>

// Problem: z [32,256,32,32] fp32, codebook [1024,256] fp32
constexpr int D_ = 256;
constexpr int K_ = 1024;
constexpr int P_ = 1024;
constexpr int N_ = 32768;

// d_out layout (float32): z_q [8388608] ++ idx-as-float [32768] ++ loss [1]
constexpr int IDX_OFF  = 8388608;
constexpr int LOSS_OFF = 8421376;

// scratch parked in d_out's z_q region (gather overwrites it LAST):
constexpr int CB16_OFF = 0;        // fp16-split swizzled cb: 262144 floats
constexpr int CN_OFF   = 262400;   // cnorm [1024]
constexpr int ZN_OFF   = 263424;   // zn [32768]
constexpr int CNT_OFF  = 296448;   // worklist counter (int)
constexpr int WL_OFF   = 296449;   // worklist [<=32768] (int row ids)

constexpr float RESCUE_MARGIN = 1e-4f;  // ~3.3 ulp(256)

typedef _Float16 half8 __attribute__((ext_vector_type(8)));
typedef float f32x4 __attribute__((ext_vector_type(4)));

__device__ __forceinline__ void stage16(const float* g, float* l) {
  // async global->LDS, 16B per lane. LDS dest must be wave-uniform base;
  // HW adds lane*16. Global src is per-lane.
  __builtin_amdgcn_global_load_lds(
      (const __attribute__((address_space(1))) unsigned int*)g,
      (__attribute__((address_space(3))) unsigned int*)l, 16, 0, 0);
}

// ---------------------------------------------------------------------------
// prep: blk<512: zn[row]=||z||^2 (PROVEN bit order); 512..1535: cnorm fp64
// (proven); 1536..1599: cb fp16-split swizzle. blk0 zeroes loss + counter.
__global__ __launch_bounds__(64) void vq_prep(const float* __restrict__ z,
                                              const float* __restrict__ cb,
                                              float* __restrict__ scratch,
                                              float* __restrict__ loss) {
  const int blk = blockIdx.x;
  const int lane = threadIdx.x;
  if (blk < 512) {
    const int n0 = blk * 64;
    const int b = n0 >> 10, p0 = n0 & (P_ - 1);
    const float* zp = z + (size_t)b * (D_ * P_) + p0 + lane;
    float a8[8];
    #pragma unroll
    for (int i = 0; i < 8; ++i) a8[i] = 0.0f;
    for (int oct = 0; oct < 32; ++oct) {
      #pragma unroll
      for (int i = 0; i < 8; ++i) {
        float v = zp[(size_t)(oct * 8 + i) * P_];
        a8[i] = fmaf(v, v, a8[i]);
      }
    }
    scratch[ZN_OFF + n0 + lane] = ((a8[0] + a8[1]) + (a8[2] + a8[3])) +
                                  ((a8[4] + a8[5]) + (a8[6] + a8[7]));
    if (blk == 0 && lane == 0) {
      *loss = 0.0f;
      ((int*)(scratch + CNT_OFF))[0] = 0;
    }
  } else if (blk < 1536) {
    const int k = blk - 512;
    const float* row = cb + (size_t)k * D_;
    double s = 0.0;
    #pragma unroll
    for (int i = 0; i < 4; ++i) {
      double v = (double)row[lane + i * 64];
      s = fma(v, v, s);
    }
    #pragma unroll
    for (int off = 32; off; off >>= 1) s += __shfl_down(s, off, 64);
    if (lane == 0) scratch[CN_OFF + k] = (float)s;
  } else {
    const int kt = blk - 1536;
    const int k = kt * 16 + (lane & 15);
    const int quad = lane >> 4;
    _Float16* cw = (_Float16*)(scratch + CB16_OFF);
    for (int ds = 0; ds < 8; ++ds) {
      const float* src = cb + (size_t)k * D_ + ds * 32 + quad * 8;
      half8 h, lo;
      #pragma unroll
      for (int j = 0; j < 8; ++j) {
        const float v = src[j] * 1024.0f;   // scale keeps lo out of subnormals
        const _Float16 hh = (_Float16)v;
        h[j] = hh;
        lo[j] = (_Float16)(v - (float)hh);
      }
      const int s = kt * 8 + ds;
      *(half8*)(cw + ((size_t)(s * 2 + 0) * 64 + lane) * 8) = h;
      *(half8*)(cw + ((size_t)(s * 2 + 1) * 64 + lane) * 8) = lo;
    }
  }
}

// ---------------------------------------------------------------------------
// main: fp16-split MFMA distance + argmin + worklist flagging.
// R11 = R2's per-wave shape x R1's occupancy. 256-thread blocks, grid 512
// (2 blocks/CU, 8 waves/CU = 2/SIMD). Wave w: rows (w&1)*32..+32 as two
// 16-row tiles, codes (w>>1)*512..+512 (row-split x K-split). Per wave per
// phase: 16 ds_read_b128 feed 48 MFMA in 6 independent chains -> per-CU
// LDS 1024 cy < MFMA 1862 cy (MFMA-bound; R1 was inverted). Two 16 KiB
// tile streams per block, double-buffered via global_load_lds; vmcnt(0) at
// phase top retires stages issued a FULL PHASE earlier (not a fresh-load
// drain). Exact cross-wave top-2 merge through LDS at the end keeps
// argmin + rescue worklist bit-identical to a full-K sweep.
__global__ __launch_bounds__(256, 2) void vq_mfma(const float* __restrict__ z,
                                                  float* __restrict__ scratch,
                                                  float* __restrict__ idxf) {
  const int t = threadIdx.x;
  const int w = t >> 6;
  const int l = t & 63;
  const int quad = l >> 4;
  const int col = l & 15;
  const int rh = w & 1;        // row half: rows rh*32..rh*32+32
  const int cs = w >> 1;       // code stream: codes cs*512..cs*512+512
  const int n0 = blockIdx.x * 64;
  const int b = n0 >> 10;
  const int p0 = n0 & (P_ - 1);

  const float* __restrict__ cbsw_f = scratch + CB16_OFF;
  const float* __restrict__ cnorm = scratch + CN_OFF;
  const float* __restrict__ zn = scratch + ZN_OFF;

  __shared__ alignas(16) float Bbuf[2][2][4096];  // [stream][parity] 16 KiB
  __shared__ alignas(16) float cnLds[1024];       // cnorm copy
  __shared__ float sM1[4][32];                    // cross-wave merge
  __shared__ float sM2[4][32];
  __shared__ int   sI1[4][32];
  float* Azs = &Bbuf[0][1][0];  // prologue alias [64][33]=2112 fl < 4096.
                                // Bbuf[*][1] first written by stage issued in
                                // phase 0 (after barrier); A frags are already
                                // consumed into regs by then => no overlap.

  // cnorm -> LDS (visibility sealed by the prologue __syncthreads below)
  *(float4*)(cnLds + t * 4) = *(const float4*)(cnorm + t * 4);

  // zn for this wave's rows (additive per-row constant)
  float znr[2][4];
  #pragma unroll
  for (int rt = 0; rt < 2; ++rt) {
    const float4 znv = *(const float4*)(zn + n0 + rh * 32 + rt * 16 + quad * 4);
    znr[rt][0] = znv.x; znr[rt][1] = znv.y;
    znr[rt][2] = znv.z; znr[rt][3] = znv.w;
  }

  // ---- A prologue (R1-proven, 4 waves): stage z 32-d chunks, split ----
  half8 Ah[2][8], Al[2][8];
  const int dl0 = w * 8;
  for (int ds = 0; ds < 8; ++ds) {
    __syncthreads();
    #pragma unroll
    for (int i = 0; i < 8; ++i) {
      const int dloc = dl0 + i;   // 4 waves x 8 d cover the 32-d chunk
      Azs[l * 33 + dloc] =
          z[(size_t)b * (D_ * P_) + (size_t)(ds * 32 + dloc) * P_ + p0 + l];
    }
    __syncthreads();
    #pragma unroll
    for (int rt = 0; rt < 2; ++rt) {
      const float* src = &Azs[(rh * 32 + rt * 16 + col) * 33 + quad * 8];
      half8 h, lo;
      #pragma unroll
      for (int j = 0; j < 8; ++j) {
        const float v = src[j];
        const _Float16 hh = (_Float16)v;
        h[j] = hh;
        lo[j] = (_Float16)(v - (float)hh);
      }
      Ah[rt][ds] = h;   // consumed here => ds_reads retired pre-loop
      Al[rt][ds] = lo;
    }
  }

  // drain prologue VMEM so in-loop vmcnt tracks ONLY stage16 ops
  asm volatile("s_waitcnt vmcnt(0)" ::: "memory");

  // ---- prologue stage: tile 0 of own stream (8 chunks/wave) ----
  const int ch0 = rh * 8;   // waves {0,2} chunks 0-7, {1,3} chunks 8-15
  const float* gsbase = cbsw_f + (size_t)cs * 32 * 4096 + l * 4;
  #pragma unroll
  for (int j = 0; j < 8; ++j) {
    const int chunk = ch0 + j;
    stage16(gsbase + chunk * 256, &Bbuf[cs][0][chunk * 256]);
  }

  float m1[2][4], m2v[2][4];
  int i1[2][4];
  #pragma unroll
  for (int rt = 0; rt < 2; ++rt)
    #pragma unroll
    for (int r = 0; r < 4; ++r) { m1[rt][r] = 1e30f; m2v[rt][r] = 1e30f; i1[rt][r] = 0; }

  float* bcur = &Bbuf[cs][0][0];
  float* bnxt = &Bbuf[cs][1][0];
  const float* cnp = cnLds + cs * 512 + col;
  int kg = cs * 512 + col;

  for (int p = 0; p < 32; ++p) {
    // stage(p) was issued one full phase ago (prologue for p=0) -> this
    // drain waits on long-landed loads, then the barrier publishes the
    // tile to both consumer waves and retires readers of the stage target.
    asm volatile("s_waitcnt vmcnt(0)" ::: "memory");
    __builtin_amdgcn_s_barrier();
    __builtin_amdgcn_sched_barrier(0);

    if (p < 31) {   // stage tile p+1 of own stream into the other parity
      const float* gsp = gsbase + (size_t)(p + 1) * 4096;
      #pragma unroll
      for (int j = 0; j < 8; ++j) {
        const int chunk = ch0 + j;
        stage16(gsp + chunk * 256, bnxt + chunk * 256);
      }
    }

    const float cnf = *cnp;

    f32x4 aH0 = {0.f,0.f,0.f,0.f}, aM0 = {0.f,0.f,0.f,0.f}, aL0 = {0.f,0.f,0.f,0.f};
    f32x4 aH1 = {0.f,0.f,0.f,0.f}, aM1 = {0.f,0.f,0.f,0.f}, aL1 = {0.f,0.f,0.f,0.f};

    __builtin_amdgcn_s_setprio(1);
    #pragma unroll
    for (int ds = 0; ds < 8; ++ds) {
      const half8 bh = *(const half8*)(bcur + (ds * 2 + 0) * 256 + l * 4);
      const half8 bl = *(const half8*)(bcur + (ds * 2 + 1) * 256 + l * 4);
      // 6 mutually independent MFMA chains (3 splits x 2 row-tiles)
      aH0 = __builtin_amdgcn_mfma_f32_16x16x32_f16(Ah[0][ds], bh, aH0, 0, 0, 0);
      aH1 = __builtin_amdgcn_mfma_f32_16x16x32_f16(Ah[1][ds], bh, aH1, 0, 0, 0);
      aM0 = __builtin_amdgcn_mfma_f32_16x16x32_f16(Ah[0][ds], bl, aM0, 0, 0, 0);
      aM1 = __builtin_amdgcn_mfma_f32_16x16x32_f16(Ah[1][ds], bl, aM1, 0, 0, 0);
      aL0 = __builtin_amdgcn_mfma_f32_16x16x32_f16(Al[0][ds], bh, aL0, 0, 0, 0);
      aL1 = __builtin_amdgcn_mfma_f32_16x16x32_f16(Al[1][ds], bh, aL1, 0, 0, 0);
    }
    __builtin_amdgcn_s_setprio(0);

    #pragma unroll
    for (int r = 0; r < 4; ++r) {
      const float s0 = fmaf((aH0[r] + aM0[r]) + aL0[r], -0x1p-9f, znr[0][r] + cnf);
      if (s0 < m1[0][r]) { m2v[0][r] = m1[0][r]; m1[0][r] = s0; i1[0][r] = kg; }  // k asc: strict <
      else if (s0 < m2v[0][r]) m2v[0][r] = s0;
      const float s1 = fmaf((aH1[r] + aM1[r]) + aL1[r], -0x1p-9f, znr[1][r] + cnf);
      if (s1 < m1[1][r]) { m2v[1][r] = m1[1][r]; m1[1][r] = s1; i1[1][r] = kg; }
      else if (s1 < m2v[1][r]) m2v[1][r] = s1;
    }

    cnp += 16;
    kg += 16;
    float* tmp = bcur; bcur = bnxt; bnxt = tmp;
  }

  // ---- cross-col top-2 butterfly (exact set merge, order-independent) ----
  #pragma unroll
  for (int off = 1; off <= 8; off <<= 1) {
    #pragma unroll
    for (int rt = 0; rt < 2; ++rt)
      #pragma unroll
      for (int r = 0; r < 4; ++r) {
        const float o1 = __shfl_xor(m1[rt][r], off, 64);
        const float o2 = __shfl_xor(m2v[rt][r], off, 64);
        const int oi = __shfl_xor(i1[rt][r], off, 64);
        if (o1 < m1[rt][r]) { m2v[rt][r] = fminf(m1[rt][r], o2); m1[rt][r] = o1; i1[rt][r] = oi; }
        else if (o1 == m1[rt][r]) { i1[rt][r] = min(i1[rt][r], oi); m2v[rt][r] = m1[rt][r]; }
        else { m2v[rt][r] = fminf(m2v[rt][r], o1); }
      }
  }

  // ---- cross-wave merge: waves (w, w^2) hold same rows, disjoint codes ----
  if (col == 0) {
    #pragma unroll
    for (int rt = 0; rt < 2; ++rt)
      #pragma unroll
      for (int r = 0; r < 4; ++r) {
        const int rl = rt * 16 + quad * 4 + r;
        sM1[w][rl] = m1[rt][r];
        sM2[w][rl] = m2v[rt][r];
        sI1[w][rl] = i1[rt][r];
      }
  }
  __syncthreads();
  if (w < 2 && col == 0) {
    int* cnt = (int*)(scratch + CNT_OFF);
    int* wl = (int*)(scratch + WL_OFF);
    #pragma unroll
    for (int rt = 0; rt < 2; ++rt)
      #pragma unroll
      for (int r = 0; r < 4; ++r) {
        const int rl = rt * 16 + quad * 4 + r;
        float a1 = sM1[w][rl], a2 = sM2[w][rl];
        int ai = sI1[w][rl];
        const float o1 = sM1[w + 2][rl], o2 = sM2[w + 2][rl];
        const int oi = sI1[w + 2][rl];
        // exact top-2 of union (same algebra as the butterfly step)
        if (o1 < a1) { a2 = fminf(a1, o2); a1 = o1; ai = oi; }
        else if (o1 == a1) { ai = min(ai, oi); a2 = a1; }
        else { a2 = fminf(a2, o1); }
        const int n = n0 + w * 32 + rl;
        idxf[n] = (float)ai;
        if (a2 - a1 < RESCUE_MARGIN) {
          const int pos = atomicAdd(cnt, 1);
          wl[pos] = n;
        }
      }
  }
}

// ---------------------------------------------------------------------------
// rescue (BATCHED): 8 rows per codebook sweep. Stage 8 z-rows in LDS; thread
// owns k = 4*tid..4*tid+3 (one pass covers K=1024) with 8x4 = 32 independent
// fma chains -> per d4-step: 4 global float4 + 8 LDS broadcasts feed 128
// fmas (latency hidden by arithmetic, nothing for the compiler to fight).
// Bit-exactness: per (row,k) chain is ascending-d sequential; k ascending
// per thread (strict <); (value,index)-lexicographic block reduction.
__global__ __launch_bounds__(256, 4) void vq_rescue(const float* __restrict__ z,
                                                    const float* __restrict__ cb,
                                                    const float* __restrict__ scratch,
                                                    float* __restrict__ idxf) {
  const int tid = threadIdx.x;
  const float* cnorm = scratch + CN_OFF;
  const float* zn = scratch + ZN_OFF;
  const int count = ((const int*)(scratch + CNT_OFF))[0];
  const int* wl = (const int*)(scratch + WL_OFF);

  __shared__ alignas(16) float zb[8][D_];
  __shared__ int nrow[8];
  __shared__ float rv[256];
  __shared__ int ri[256];

  for (int base = blockIdx.x * 8; base < count; base += gridDim.x * 8) {
    const int take = min(8, count - base);
    if (tid < 8) nrow[tid] = wl[base + (tid < take ? tid : 0)];
    __syncthreads();
    #pragma unroll
    for (int r = 0; r < 8; ++r) {
      const int n = nrow[r];
      const int b = n >> 10, p = n & (P_ - 1);
      zb[r][tid] = z[(size_t)b * (D_ * P_) + (size_t)tid * P_ + p];
    }
    __syncthreads();

    const int k0 = tid * 4;
    const float4* __restrict__ cr0 = (const float4*)(cb + (size_t)(k0 + 0) * D_);
    const float4* __restrict__ cr1 = (const float4*)(cb + (size_t)(k0 + 1) * D_);
    const float4* __restrict__ cr2 = (const float4*)(cb + (size_t)(k0 + 2) * D_);
    const float4* __restrict__ cr3 = (const float4*)(cb + (size_t)(k0 + 3) * D_);

    float acc[8][4];
    #pragma unroll
    for (int r = 0; r < 8; ++r)
      #pragma unroll
      for (int j = 0; j < 4; ++j) acc[r][j] = 0.0f;

    for (int d4 = 0; d4 < 64; ++d4) {
      const float4 v0 = cr0[d4], v1 = cr1[d4], v2 = cr2[d4], v3 = cr3[d4];
      #pragma unroll
      for (int r = 0; r < 8; ++r) {
        const float4 zv = ((const float4*)zb[r])[d4];   // LDS broadcast
        acc[r][0] = fmaf(zv.x, v0.x, acc[r][0]);
        acc[r][0] = fmaf(zv.y, v0.y, acc[r][0]);
        acc[r][0] = fmaf(zv.z, v0.z, acc[r][0]);
        acc[r][0] = fmaf(zv.w, v0.w, acc[r][0]);
        acc[r][1] = fmaf(zv.x, v1.x, acc[r][1]);
        acc[r][1] = fmaf(zv.y, v1.y, acc[r][1]);
        acc[r][1] = fmaf(zv.z, v1.z, acc[r][1]);
        acc[r][1] = fmaf(zv.w, v1.w, acc[r][1]);
        acc[r][2] = fmaf(zv.x, v2.x, acc[r][2]);
        acc[r][2] = fmaf(zv.y, v2.y, acc[r][2]);
        acc[r][2] = fmaf(zv.z, v2.z, acc[r][2]);
        acc[r][2] = fmaf(zv.w, v2.w, acc[r][2]);
        acc[r][3] = fmaf(zv.x, v3.x, acc[r][3]);
        acc[r][3] = fmaf(zv.y, v3.y, acc[r][3]);
        acc[r][3] = fmaf(zv.z, v3.z, acc[r][3]);
        acc[r][3] = fmaf(zv.w, v3.w, acc[r][3]);
      }
    }

    for (int r = 0; r < 8; ++r) {
      const int n = nrow[r];
      const float zA = zn[n];
      float bv = 1e30f;
      int bi = 0x7fffffff;
      #pragma unroll
      for (int j = 0; j < 4; ++j) {               // k ascending -> strict <
        const float A = zA + cnorm[k0 + j];
        const float s = A - 2.0f * acc[r][j];
        if (s < bv) { bv = s; bi = k0 + j; }
      }
      rv[tid] = bv; ri[tid] = bi;
      __syncthreads();
      for (int off = 128; off >= 1; off >>= 1) {
        if (tid < off) {
          const float ov = rv[tid + off];
          const int oi = ri[tid + off];
          if (ov < rv[tid] || (ov == rv[tid] && oi < ri[tid])) { rv[tid] = ov; ri[tid] = oi; }
        }
        __syncthreads();
      }
      if (tid == 0 && r < take) idxf[n] = (float)ri[0];
      __syncthreads();
    }
  }
}

// ---------------------------------------------------------------------------
// gather: z_q = codebook[idx] into NCHW + loss; STE write out = z + (v - z).
__global__ __launch_bounds__(256) void vq_gather(const float* __restrict__ z,
                                                 const float* __restrict__ cb,
                                                 const float* __restrict__ idxf,
                                                 float* __restrict__ out,
                                                 float* __restrict__ loss) {
  const int tid = threadIdx.x;
  const int lane = tid & 63;
  const int w = tid >> 6;
  const int n0 = blockIdx.x * 64;
  const int b = n0 >> 10;
  const int p0 = n0 & (P_ - 1);
  const int p = p0 + lane;

  const int idx = (int)(idxf[n0 + lane] + 0.5f);
  const float4* crow4 = (const float4*)(cb + (size_t)idx * D_);
  const size_t base = (size_t)b * (D_ * P_) + p;

  float acc = 0.0f;
  #pragma unroll 4
  for (int ci = 0; ci < 16; ++ci) {
    const float4 v = crow4[w * 16 + ci];
    const int c = w * 64 + ci * 4;
    const float vv[4] = {v.x, v.y, v.z, v.w};
    #pragma unroll
    for (int u = 0; u < 4; ++u) {
      const size_t a = base + (size_t)(c + u) * P_;
      const float zv = z[a];
      const float d = vv[u] - zv;
      out[a] = zv + d;                  // fl32 STE, bit-exact
      acc = fmaf(d, d, acc);
    }
  }
  #pragma unroll
  for (int off = 32; off; off >>= 1) acc += __shfl_down(acc, off, 64);
  __shared__ float wsum[4];
  if (lane == 0) wsum[w] = acc;
  __syncthreads();
  if (tid == 0) {
    float s = wsum[0] + wsum[1] + wsum[2] + wsum[3];
    atomicAdd(loss, s * (1.25f / 8388608.0f));
  }
}

// ---------------------------------------------------------------------------
extern "C" void kernel_launch(void* const* d_in, const int* in_sizes, int n_in,
                              void* d_out, int out_size, void* d_ws, size_t ws_size,
                              hipStream_t stream) {
  const float* z = (const float*)d_in[0];
  const float* cb = (const float*)d_in[1];
  float* out = (float*)d_out;

  vq_prep<<<1600, 64, 0, stream>>>(z, cb, out, out + LOSS_OFF);
  vq_mfma<<<N_ / 64, 256, 0, stream>>>(z, out, out + IDX_OFF);
  vq_rescue<<<128, 256, 0, stream>>>(z, cb, out, out + IDX_OFF);
  vq_gather<<<N_ / 64, 256, 0, stream>>>(z, cb, out + IDX_OFF, out, out + LOSS_OFF);
}